// Round 10
// baseline (80.842 us; speedup 1.0000x reference)
//
#include <hip/hip_runtime.h>
#include <math.h>

// Problem constants
#define QDIM 512     // 2^9 state dim
#define DD   128     // K*C_IN = input dim of quadratic form
#define LIN  4096
#define LOUT 4089    // (4096 - 7 - 1)/1 + 1
#define NC   16      // C_IN
#define NB   16      // batch

typedef __attribute__((ext_vector_type(8))) short bf16x8;
typedef __attribute__((ext_vector_type(4))) float f32x4;

// Scratch in device globals (NOT d_ws) — R5 lesson. Every element rewritten
// each call before read. R8 lesson: no single-line grid barriers.
__device__ float  g_B[QDIM * DD];
__device__ float  g_C[QDIM * DD];
__device__ unsigned short g_Qh[DD * DD];   // bf16 hi part of Q
__device__ unsigned short g_Ql[DD * DD];   // bf16 residual of Q

// ---- bf16 helpers (RNE) ----
__device__ __forceinline__ unsigned short f2bf(float f) {
  union { float f; unsigned u; } v; v.f = f;
  unsigned u = v.u + 0x7FFFu + ((v.u >> 16) & 1u);
  return (unsigned short)(u >> 16);
}
__device__ __forceinline__ float bf2f(unsigned short h) {
  union { unsigned u; float f; } v; v.u = ((unsigned)h) << 16;
  return v.f;
}

// ---------------------------------------------------------------------------
// Precompute. A = (E*R3*E*R2*E*R1)[:, :128]; row i of E*R*W = (R^T e_i)^T W
// via transposed butterflies in REVERSE qubit order on the E-row in LDS.
// 4-row blocking: each block processes 4 output rows, reads W once.
// ---------------------------------------------------------------------------

// Butterfly 4 rows at once; one barrier per step.
__device__ __forceinline__ void butterfly_T4(float er[4][QDIM],
                                             const float* theta, int l, int p) {
  #pragma unroll
  for (int qq = 0; qq < 9; ++qq) {
    int q = 8 - qq;                    // reverse order for transpose
    float half = theta[l * 9 + q] * 0.5f;
    float c = cosf(half), s = sinf(half);
    int right = QDIM >> (q + 1);
    int a = p >> (8 - q);
    int r = p & (right - 1);
    int i0 = (a * 2) * right + r;
    int i1 = i0 + right;
    #pragma unroll
    for (int rr = 0; rr < 4; ++rr) {
      float v0 = er[rr][i0], v1 = er[rr][i1];
      er[rr][i0] = c * v0 + s * v1;    // transposed 2x2
      er[rr][i1] = c * v1 - s * v0;
    }
    __syncthreads();
  }
}

// W1 rows 4i..4i+3: (R1^T e_row)[0:128] -> g_B
__global__ __launch_bounds__(256) void w1_kernel(const float* __restrict__ E,
                                                 const float* __restrict__ theta) {
  __shared__ float er[4][QDIM];
  int i0 = blockIdx.x * 4;
  int p = threadIdx.x;
  #pragma unroll
  for (int rr = 0; rr < 4; ++rr) {
    er[rr][p]       = E[(i0 + rr) * QDIM + p];
    er[rr][p + 256] = E[(i0 + rr) * QDIM + p + 256];
  }
  __syncthreads();
  butterfly_T4(er, theta, 0, p);
  if (p < DD) {
    #pragma unroll
    for (int rr = 0; rr < 4; ++rr) g_B[(i0 + rr) * DD + p] = er[rr][p];
  }
}

// dst rows 4i..4i+3 = (R_l^T e_row)^T * src.  sel: 0 = g_B->g_C, 1 = g_C->g_B.
__global__ __launch_bounds__(256) void mm_fused_kernel(const float* __restrict__ E,
                                                       const float* __restrict__ theta,
                                                       int l, int sel) {
  const float* W = sel ? g_C : g_B;
  float* D       = sel ? g_B : g_C;
  __shared__ float er[4][QDIM];
  __shared__ float part[4][DD];
  int i0 = blockIdx.x * 4;
  int tid = threadIdx.x;
  #pragma unroll
  for (int rr = 0; rr < 4; ++rr) {
    er[rr][tid]       = E[(i0 + rr) * QDIM + tid];
    er[rr][tid + 256] = E[(i0 + rr) * QDIM + tid + 256];
  }
  __syncthreads();
  butterfly_T4(er, theta, l, tid);

  int j = tid & 127, h = tid >> 7;
  float a0[4] = {0.f, 0.f, 0.f, 0.f};
  int m0 = h * 256;
  #pragma unroll 4
  for (int m = m0; m < m0 + 256; ++m) {
    float wv = W[m * DD + j];
    #pragma unroll
    for (int rr = 0; rr < 4; ++rr) a0[rr] = fmaf(er[rr][m], wv, a0[rr]);
  }
  if (h == 1) {
    #pragma unroll
    for (int rr = 0; rr < 4; ++rr) part[rr][j] = a0[rr];
  }
  __syncthreads();
  if (h == 0) {
    #pragma unroll
    for (int rr = 0; rr < 4; ++rr)
      D[(i0 + rr) * DD + j] = a0[rr] + part[rr][j];
  }
}

// Q[j1][j2] = sum_i sgn(i) A[i][j1] A[i][j2]; A = g_B. Emit bf16 hi/lo.
__global__ __launch_bounds__(256) void formq_kernel() {
  const float* A = g_B;
  __shared__ float colA[QDIM];
  __shared__ float part[DD];
  int j1 = blockIdx.x;
  int tid = threadIdx.x;
  int j2 = tid & 127, h = tid >> 7;
  for (int i = tid; i < QDIM; i += 256) {
    float sgn = (i < 256) ? 1.0f : -1.0f;
    colA[i] = sgn * A[i * DD + j1];
  }
  __syncthreads();
  float a0 = 0.f, a1 = 0.f, a2 = 0.f, a3 = 0.f;
  int i0 = h * 256;
  #pragma unroll 8
  for (int i = i0; i < i0 + 256; i += 4) {
    a0 = fmaf(colA[i + 0], A[(i + 0) * DD + j2], a0);
    a1 = fmaf(colA[i + 1], A[(i + 1) * DD + j2], a1);
    a2 = fmaf(colA[i + 2], A[(i + 2) * DD + j2], a2);
    a3 = fmaf(colA[i + 3], A[(i + 3) * DD + j2], a3);
  }
  float sum = (a0 + a1) + (a2 + a3);
  if (h == 1) part[j2] = sum;
  __syncthreads();
  if (h == 0) {
    sum += part[j2];
    unsigned short hi = f2bf(sum);
    unsigned short lo = f2bf(sum - bf2f(hi));
    g_Qh[j1 * DD + j2] = hi;
    g_Ql[j1 * DD + j2] = lo;
  }
}

// ---------------------------------------------------------------------------
// Main pass via MFMA split-bf16 (R9 numerics), t-tile = 128:
// 4 waves x 2 M-tiles each; B-frags (Q rows) shared across the 2 M-tiles
// -> half the Q L2 traffic. C layout: col=lane&15, row=(lane>>4)*4+reg.
// ---------------------------------------------------------------------------
__global__ __launch_bounds__(256, 2) void quad_mfma_kernel(const float* __restrict__ x,
                                                           float* __restrict__ out) {
  __shared__ float xs[NC][136];     // 135 used (128 t + 7 halo)
  int b = blockIdx.x;
  int t0 = blockIdx.y * 128;
  int tid = threadIdx.x;
  int lane = tid & 63;
  int w = tid >> 6;                 // wave id: rows [w*32, w*32+32)
  const float* xb = x + (size_t)b * NC * LIN;

  for (int idx = tid; idx < NC * 135; idx += 256) {
    int c = idx / 135, o = idx % 135;
    int g = t0 + o;
    xs[c][o] = (g < LIN) ? xb[c * LIN + g] : 0.0f;
  }
  __syncthreads();

  int lrow = lane & 15;
  int lgrp = lane >> 4;

  f32x4 acc[2][8];
  #pragma unroll
  for (int m = 0; m < 2; ++m)
    #pragma unroll
    for (int n = 0; n < 8; ++n) acc[m][n] = (f32x4){0.f, 0.f, 0.f, 0.f};

  #pragma unroll
  for (int kb = 0; kb < 4; ++kb) {
    int c = kb * 4 + lgrp;
    bf16x8 a_hi[2], a_lo[2];
    #pragma unroll
    for (int m = 0; m < 2; ++m) {
      int tl = (w * 2 + m) * 16 + lrow;
      #pragma unroll
      for (int e = 0; e < 8; ++e) {
        float v = xs[c][tl + e];
        unsigned short hh = f2bf(v);
        unsigned short ll = f2bf(v - bf2f(hh));
        a_hi[m][e] = (short)hh;
        a_lo[m][e] = (short)ll;
      }
    }
    #pragma unroll
    for (int n = 0; n < 8; ++n) {
      int off = (n * 16 + lrow) * DD + kb * 32 + lgrp * 8;
      bf16x8 b_hi = *(const bf16x8*)(g_Qh + off);
      bf16x8 b_lo = *(const bf16x8*)(g_Ql + off);
      #pragma unroll
      for (int m = 0; m < 2; ++m) {
        acc[m][n] = __builtin_amdgcn_mfma_f32_16x16x32_bf16(a_hi[m], b_hi, acc[m][n], 0, 0, 0);
        acc[m][n] = __builtin_amdgcn_mfma_f32_16x16x32_bf16(a_hi[m], b_lo, acc[m][n], 0, 0, 0);
        acc[m][n] = __builtin_amdgcn_mfma_f32_16x16x32_bf16(a_lo[m], b_hi, acc[m][n], 0, 0, 0);
      }
    }
  }

  // Epilogue: lane holds U[t=(w*2+m)*16+lgrp*4+r][i=n*16+lrow].
  float pd[2][4] = {{0.f,0.f,0.f,0.f},{0.f,0.f,0.f,0.f}};
  float pn[2][4] = {{0.f,0.f,0.f,0.f},{0.f,0.f,0.f,0.f}};
  #pragma unroll
  for (int n = 0; n < 8; ++n) {
    int i = n * 16 + lrow;
    int cc = i >> 3, ko = i & 7;
    #pragma unroll
    for (int m = 0; m < 2; ++m) {
      #pragma unroll
      for (int r = 0; r < 4; ++r) {
        int tl = (w * 2 + m) * 16 + lgrp * 4 + r;
        float v = xs[cc][tl + ko];
        pd[m][r] = fmaf(acc[m][n][r], v, pd[m][r]);
        pn[m][r] = fmaf(v, v, pn[m][r]);
      }
    }
  }
  #pragma unroll
  for (int m = 0; m < 2; ++m)
    #pragma unroll
    for (int r = 0; r < 4; ++r) {
      #pragma unroll
      for (int msk = 1; msk < 16; msk <<= 1) {
        pd[m][r] += __shfl_xor(pd[m][r], msk);
        pn[m][r] += __shfl_xor(pn[m][r], msk);
      }
    }
  if (lrow == 0) {
    #pragma unroll
    for (int m = 0; m < 2; ++m)
      #pragma unroll
      for (int r = 0; r < 4; ++r) {
        int t = t0 + (w * 2 + m) * 16 + lgrp * 4 + r;
        if (t < LOUT) out[(size_t)b * LOUT + t] = pd[m][r] / (pn[m][r] + 1e-12f);
      }
  }
}

// ---------------------------------------------------------------------------

extern "C" void kernel_launch(void* const* d_in, const int* in_sizes, int n_in,
                              void* d_out, int out_size, void* d_ws, size_t ws_size,
                              hipStream_t stream) {
  const float* x     = (const float*)d_in[0];   // (16,16,4096) f32
  const float* E     = (const float*)d_in[1];   // (512,512)    f32
  const float* theta = (const float*)d_in[2];   // (3,9)        f32
  float* out = (float*)d_out;                   // (16,1,1,4089) f32
  (void)d_ws; (void)ws_size;

  w1_kernel<<<QDIM / 4, 256, 0, stream>>>(E, theta);              // -> g_B
  mm_fused_kernel<<<QDIM / 4, 256, 0, stream>>>(E, theta, 1, 0);  // g_B -> g_C
  mm_fused_kernel<<<QDIM / 4, 256, 0, stream>>>(E, theta, 2, 1);  // g_C -> g_B
  formq_kernel<<<DD, 256, 0, stream>>>();                         // g_B -> g_Qh/g_Ql
  quad_mfma_kernel<<<dim3(NB, 32), 256, 0, stream>>>(x, out);
}